// Round 6
// baseline (385.200 us; speedup 1.0000x reference)
//
#include <hip/hip_runtime.h>

typedef _Float16 half2_t __attribute__((ext_vector_type(2)));
typedef unsigned int uint_t;
typedef uint_t uint4v __attribute__((ext_vector_type(4)));

#define B_  64
#define T_  256
#define F_  16
#define H_  128
#define LOG2E 1.44269504f

__device__ __forceinline__ float rcp_(float x)  { return __builtin_amdgcn_rcpf(x); }
__device__ __forceinline__ float sigm(float x)  { return rcp_(1.0f + __expf(-x)); }
__device__ __forceinline__ float tanh_(float x) { return 2.0f * rcp_(1.0f + __expf(-2.0f * x)) - 1.0f; }

#if __has_builtin(__builtin_amdgcn_fdot2)
__device__ __forceinline__ float dot2(uint_t w, uint_t h, float a) {
    return __builtin_amdgcn_fdot2(__builtin_bit_cast(half2_t, w),
                                  __builtin_bit_cast(half2_t, h), a, false);
}
#else
__device__ __forceinline__ float dot2(uint_t w, uint_t h, float a) {
    half2_t W = __builtin_bit_cast(half2_t, w), H = __builtin_bit_cast(half2_t, h);
    return a + (float)W[0] * (float)H[0] + (float)W[1] * (float)H[1];
}
#endif

// quad butterfly add (0xB1 = xor1, 0x4E = xor2) and quad mov (lane0 pulls from quad peer)
template <int CTRL>
__device__ __forceinline__ float qadd(float v) {
    int t = __builtin_amdgcn_update_dpp(0, __builtin_bit_cast(int, v), CTRL, 0xF, 0xF, true);
    return v + __builtin_bit_cast(float, t);
}
template <int CTRL>
__device__ __forceinline__ float dmov(float v) {
    int t = __builtin_amdgcn_update_dpp(0, __builtin_bit_cast(int, v), CTRL, 0xF, 0xF, true);
    return __builtin_bit_cast(float, t);
}

// Kernel 0: pair batches by window midpoint (parallel O(64^2) ranking; no serial sort).
// pairs[p] = { bA<<8|bB, sA<<16|eA, sB<<16|eB, 0 }
__global__ void make_sched(const int* __restrict__ index, int* __restrict__ pairs) {
    __shared__ int ss[B_], ee[B_], mid[B_], bo[B_];
    const int t = threadIdx.x;           // 64 threads
    int s = index[2 * t], e = index[2 * t + 1];
    ss[t] = s; ee[t] = e; mid[t] = s + e;
    __syncthreads();
    int m = mid[t], r = 0;
    for (int j = 0; j < B_; ++j) r += (mid[j] < m) || (mid[j] == m && j < t);
    bo[r] = t;
    __syncthreads();
    if (t < 32) {
        int bA = bo[2 * t], bB = bo[2 * t + 1];
        int4 v;
        v.x = (bA << 8) | bB;
        v.y = (ss[bA] << 16) | ee[bA];
        v.z = (ss[bB] << 16) | ee[bB];
        v.w = 0;
        ((int4*)pairs)[t] = v;
    }
}

// Kernel 1: repack W_hh [F,4H,H] fp32 -> f16-pair layout keyed to the main kernel's
// per-thread register file (thread (i,ks): rows {i+128m}, k-slice [32ks,32ks+32)).
// Widened to 128 blocks (f x 8 q-chunks).
__global__ void repack_w(const float* __restrict__ whh, uint_t* __restrict__ wt) {
    const int f = blockIdx.x >> 3, qc = blockIdx.x & 7, tid = threadIdx.x;
    const int i = tid >> 2, ks = tid & 3;
    const float* base = whh + (size_t)f * 512 * 128;
#pragma unroll
    for (int qq = 0; qq < 2; ++qq) {
        const int q = qc * 2 + qq;
        uint_t tmp[4];
#pragma unroll
        for (int e = 0; e < 4; ++e) {
            int dd = q * 4 + e, m = dd >> 4, kk = dd & 15;
            int row = i + 128 * m, k0 = 32 * ks + 2 * kk;
            half2_t h = { (_Float16)base[row * 128 + k0], (_Float16)base[row * 128 + k0 + 1] };
            tmp[e] = __builtin_bit_cast(uint_t, h);
        }
        uint4 out = { tmp[0], tmp[1], tmp[2], tmp[3] };
        ((uint4*)wt)[((size_t)f * 16 + q) * 512 + tid] = out;
    }
}

// Kernel 2: 512 blocks = 16 f x 32 pairs; each block runs TWO chains (same f -> same
// weights) in lockstep over the union window. Thread (i,ks): 4 gate rows x 32-k slice
// per batch. Lane ks computes only gate-type ks (branchless nl), DPP-gathers to lane 0.
__global__ __launch_bounds__(512, 2) void lstm_main(
    const float* __restrict__ x, const int* __restrict__ pairs,
    const float* __restrict__ wih_g, const float* __restrict__ bias_g,
    const uint_t* __restrict__ wt, float* __restrict__ hout)
{
    __shared__ float xsh[2][T_];
    __shared__ alignas(16) unsigned short hsh[2][2][H_];   // [buf][batch][i]

    const int f = blockIdx.x >> 5, pr = blockIdx.x & 31;
    const int tid = threadIdx.x;
    const int i = tid >> 2, ks = tid & 3;

    const int4 pv = ((const int4*)pairs)[pr];
    const int bA = pv.x >> 8, bB = pv.x & 255;
    const int sA = pv.y >> 16, eA = pv.y & 0xffff;
    const int sB = pv.z >> 16, eB = pv.z & 0xffff;
    const int su = min(sA, sB), eu = max(eA, eB);

    // ---- opaque weight preload: 16 x global_load_dwordx4 (proved resident R4/R5) ----
    uint4v w[16];
    {
        const char* src = (const char*)wt + (((size_t)f * 16) * 512 + tid) * 16;
#pragma unroll
        for (int q = 0; q < 16; ++q) {
            unsigned long long addr = (unsigned long long)(src + (size_t)q * 512 * 16);
            asm volatile("global_load_dwordx4 %0, %1, off" : "=v"(w[q]) : "v"(addr));
        }
        asm volatile("s_waitcnt vmcnt(0)");
        __builtin_amdgcn_sched_barrier(0);
    }

    // per-lane gate-type constants (lane handles gate type ks for its i)
    const float wih  = wih_g[f * 512 + 128 * ks + i];
    const float bias = bias_g[f * 512 + 128 * ks + i];
    const float s1 = (ks == 2) ? -2.0f * LOG2E : -LOG2E;
    const float s2 = (ks == 2) ?  2.0f : 1.0f;
    const float s3 = (ks == 2) ? -1.0f : 0.0f;
    const bool k1 = (ks & 1) != 0, k2 = (ks & 2) != 0;

    if (tid < T_) xsh[0][tid] = x[((size_t)bA * T_ + tid) * F_ + f];
    else          xsh[1][tid - T_] = x[((size_t)bB * T_ + (tid - T_)) * F_ + f];
    if (tid < H_) { hsh[0][0][tid] = 0; hsh[0][1][tid] = 0; }

    float cA = 0.0f, cB = 0.0f, hA = 0.0f, hB = 0.0f;
    int p = 0;

    for (int t = su; t < eu; ++t) {
        __syncthreads();                    // hsh[p] (and xsh on first iter) visible
        const uint4v* hA4 = (const uint4v*)(&hsh[p][0][ks * 32]);
        const uint4v* hB4 = (const uint4v*)(&hsh[p][1][ks * 32]);
        float aA[4] = {0.f, 0.f, 0.f, 0.f}, aB[4] = {0.f, 0.f, 0.f, 0.f};
#pragma unroll
        for (int q = 0; q < 4; ++q) {
            uint4v hqA = hA4[q], hqB = hB4[q];
#pragma unroll
            for (int m = 0; m < 4; ++m) {
                uint4v wq = w[m * 4 + q];
                aA[m] = dot2(wq.x, hqA.x, aA[m]);
                aA[m] = dot2(wq.y, hqA.y, aA[m]);
                aA[m] = dot2(wq.z, hqA.z, aA[m]);
                aA[m] = dot2(wq.w, hqA.w, aA[m]);
                aB[m] = dot2(wq.x, hqB.x, aB[m]);
                aB[m] = dot2(wq.y, hqB.y, aB[m]);
                aB[m] = dot2(wq.z, hqB.z, aB[m]);
                aB[m] = dot2(wq.w, hqB.w, aB[m]);
            }
        }
#pragma unroll
        for (int m = 0; m < 4; ++m) {
            aA[m] = qadd<0xB1>(aA[m]);  aA[m] = qadd<0x4E>(aA[m]);
            aB[m] = qadd<0xB1>(aB[m]);  aB[m] = qadd<0x4E>(aB[m]);
        }
        // lane ks takes gate-type ks (static cndmask select, no dynamic indexing)
        float selA = k2 ? (k1 ? aA[3] : aA[2]) : (k1 ? aA[1] : aA[0]);
        float selB = k2 ? (k1 ? aB[3] : aB[2]) : (k1 ? aB[1] : aB[0]);
        float pA = fmaf(xsh[0][t], wih, selA + bias);
        float pB = fmaf(xsh[1][t], wih, selB + bias);
        // branchless nl: sigm for ks!=2, tanh for ks==2
        float vA = fmaf(rcp_(1.0f + __builtin_amdgcn_exp2f(pA * s1)), s2, s3);
        float vB = fmaf(rcp_(1.0f + __builtin_amdgcn_exp2f(pB * s1)), s2, s3);
        // gather i,f,g,o to lane 0 of each quad (all lanes active for DPP)
        float fA_ = dmov<0xB1>(vA), gA_ = dmov<0x4E>(vA), oA_ = dmov<0x4E>(fA_);
        float fB_ = dmov<0xB1>(vB), gB_ = dmov<0x4E>(vB), oB_ = dmov<0x4E>(fB_);
        if ((tid & 3) == 0) {
            bool mA = (t >= sA) & (t < eA);
            bool mB = (t >= sB) & (t < eB);
            float cnA = fmaf(fA_, cA, vA * gA_);
            float cnB = fmaf(fB_, cB, vB * gB_);
            cA = mA ? cnA : cA;
            cB = mB ? cnB : cB;
            float thA = fmaf(rcp_(1.0f + __builtin_amdgcn_exp2f(cA * (-2.0f * LOG2E))), 2.0f, -1.0f);
            float thB = fmaf(rcp_(1.0f + __builtin_amdgcn_exp2f(cB * (-2.0f * LOG2E))), 2.0f, -1.0f);
            hA = mA ? oA_ * thA : hA;
            hB = mB ? oB_ * thB : hB;
            _Float16 ha = (_Float16)hA, hb = (_Float16)hB;
            hsh[p ^ 1][0][i] = __builtin_bit_cast(unsigned short, ha);
            hsh[p ^ 1][1][i] = __builtin_bit_cast(unsigned short, hb);
        }
        p ^= 1;
    }
    if ((tid & 3) == 0) {
        hout[((size_t)bA * F_ + f) * H_ + i] = hA;
        hout[((size_t)bB * F_ + f) * H_ + i] = hB;
    }
}

// Kernel 3: per-batch epilogue: mean over H -> conv3 (pad 1) -> sigmoid gate -> gated fc.
__global__ void epilogue(const float* __restrict__ hout, const float* __restrict__ conv_w,
                         const float* __restrict__ fc_w, const float* __restrict__ fc_b,
                         float* __restrict__ out)
{
    const int b = blockIdx.x, t = threadIdx.x;   // 128 threads
    const int lane = t & 63, wv = t >> 6;
    __shared__ float part[2][16];
    __shared__ float gate_sh[16];

    float hv[16];
#pragma unroll
    for (int f = 0; f < 16; ++f) hv[f] = hout[((size_t)b * 16 + f) * 128 + t];

#pragma unroll
    for (int f = 0; f < 16; ++f) {
        float s = hv[f];
#pragma unroll
        for (int off = 32; off >= 1; off >>= 1) s += __shfl_down(s, off, 64);
        if (lane == 0) part[wv][f] = s;
    }
    __syncthreads();
    if (t < 16) gate_sh[t] = (part[0][t] + part[1][t]) * (1.0f / 128.0f);  // means
    __syncthreads();
    float gate = 0.0f;
    if (t < 16) {
        float l  = (t > 0)  ? gate_sh[t - 1] : 0.0f;
        float mi = gate_sh[t];
        float r  = (t < 15) ? gate_sh[t + 1] : 0.0f;
        gate = sigm(fmaf(l, conv_w[0], fmaf(mi, conv_w[1], r * conv_w[2])));
    }
    __syncthreads();
    if (t < 16) gate_sh[t] = gate;
    __syncthreads();

    float acc0 = 0.0f, acc1 = 0.0f;
    const float2* fw2 = (const float2*)fc_w;
#pragma unroll
    for (int f = 0; f < 16; ++f) {
        float hg = hv[f] * gate_sh[f];
        float2 w2 = fw2[f * 128 + t];
        acc0 = fmaf(hg, w2.x, acc0);
        acc1 = fmaf(hg, w2.y, acc1);
    }
#pragma unroll
    for (int off = 32; off >= 1; off >>= 1) {
        acc0 += __shfl_down(acc0, off, 64);
        acc1 += __shfl_down(acc1, off, 64);
    }
    if (lane == 0) { part[wv][0] = acc0; part[wv][1] = acc1; }
    __syncthreads();
    if (t == 0) {
        out[b * 2 + 0] = part[0][0] + part[1][0] + fc_b[0];
        out[b * 2 + 1] = part[0][1] + part[1][1] + fc_b[1];
    }
}

extern "C" void kernel_launch(void* const* d_in, const int* in_sizes, int n_in,
                              void* d_out, int out_size, void* d_ws, size_t ws_size,
                              hipStream_t stream) {
    const float* x      = (const float*)d_in[0];
    const int*   index  = (const int*)  d_in[1];
    const float* W_ih   = (const float*)d_in[2];
    const float* W_hh   = (const float*)d_in[3];
    const float* bias   = (const float*)d_in[4];
    const float* conv_w = (const float*)d_in[5];
    const float* fc_w   = (const float*)d_in[6];
    const float* fc_b   = (const float*)d_in[7];
    float* out = (float*)d_out;

    uint_t* wt   = (uint_t*)d_ws;                               // 2 MB
    float*  hout = (float*)((char*)d_ws + 2 * 1024 * 1024);     // 512 KB
    int*    pairs = (int*)((char*)d_ws + 2 * 1024 * 1024 + 512 * 1024); // 512 B

    make_sched<<<1, 64, 0, stream>>>(index, pairs);
    repack_w<<<128, 512, 0, stream>>>(W_hh, wt);
    lstm_main<<<512, 512, 0, stream>>>(x, pairs, W_ih, bias, wt, hout);
    epilogue<<<B_, 128, 0, stream>>>(hout, conv_w, fc_w, fc_b, out);
}

// Round 7
// 235.941 us; speedup vs baseline: 1.6326x; 1.6326x over previous
//
#include <hip/hip_runtime.h>

typedef _Float16 half_t;
typedef half_t half2_t __attribute__((ext_vector_type(2)));
typedef half_t half8  __attribute__((ext_vector_type(8)));
typedef unsigned int uint_t;
typedef uint_t uint2v __attribute__((ext_vector_type(2)));
typedef uint_t uint4v __attribute__((ext_vector_type(4)));
typedef float float4v __attribute__((ext_vector_type(4)));

#define B_  64
#define T_  256
#define F_  16
#define H_  128
#define NG  4     // batch groups
#define GB  16    // batches per group
#define LOG2E 1.44269504f

__device__ __forceinline__ float rcp_(float x)  { return __builtin_amdgcn_rcpf(x); }
__device__ __forceinline__ float sigm2(float x) { return rcp_(1.0f + __builtin_amdgcn_exp2f(x * -LOG2E)); }
__device__ __forceinline__ float tanh2(float x) { return fmaf(rcp_(1.0f + __builtin_amdgcn_exp2f(x * (-2.0f * LOG2E))), 2.0f, -1.0f); }
__device__ __forceinline__ float sigm(float x)  { return rcp_(1.0f + __expf(-x)); }

// Kernel 0: rank batches by window midpoint; groups of 16 consecutive ranks share a block
// (similar windows -> small union). gmeta[r] = {b, s, e, 0}; guni[q] = {su, eu}.
__global__ void make_sched(const int* __restrict__ index, int* __restrict__ gmeta,
                           int* __restrict__ guni) {
    __shared__ int oB[B_], oS[B_], oE[B_], mid[B_];
    const int t = threadIdx.x;                 // 64
    const int s = index[2 * t], e = index[2 * t + 1];
    mid[t] = s + e;
    __syncthreads();
    int m = mid[t], r = 0;
    for (int j = 0; j < B_; ++j) r += (mid[j] < m) || (mid[j] == m && j < t);
    oB[r] = t; oS[r] = s; oE[r] = e;
    __syncthreads();
    int4 v; v.x = oB[t]; v.y = oS[t]; v.z = oE[t]; v.w = 0;
    ((int4*)gmeta)[t] = v;
    if (t < NG) {
        int su = 1 << 30, eu = 0;
        for (int j = 0; j < GB; ++j) { su = min(su, oS[t * GB + j]); eu = max(eu, oE[t * GB + j]); }
        guni[2 * t] = su; guni[2 * t + 1] = eu;
    }
}

// Kernel 1: repack W_hh [F,4H,H] fp32 -> f16 B-fragments for mfma_f32_16x16x32_f16.
// Consuming lane `lane` of wave w, fragment q = m*4+kt, dword e2 holds f16 pair for
// k = kt*32 + (lane>>4)*8 + 2*e2 (+1), col g512 = 128*m + 16*w + (lane&15).
// Store: uint4 wt[((f*8+w)*16 + q)*64 + lane].
__global__ void repack_w(const float* __restrict__ whh, uint_t* __restrict__ wt) {
    const int f = blockIdx.x, w = blockIdx.y, tid = threadIdx.x;  // 256 threads
    const int lane = tid & 63, q4 = tid >> 6;
    const int li = lane & 15, lg = lane >> 4;
    const float* base = whh + (size_t)f * 512 * 128;
#pragma unroll
    for (int qq = 0; qq < 4; ++qq) {
        const int qf = q4 * 4 + qq;
        const int m = qf >> 2, kt = qf & 3;
        const int g512 = 128 * m + 16 * w + li;
        uint_t tmp[4];
#pragma unroll
        for (int e2 = 0; e2 < 4; ++e2) {
            int k = kt * 32 + lg * 8 + 2 * e2;
            half2_t h;
            h[0] = (half_t)base[g512 * 128 + k];
            h[1] = (half_t)base[g512 * 128 + k + 1];
            tmp[e2] = __builtin_bit_cast(uint_t, h);
        }
        uint4 out = { tmp[0], tmp[1], tmp[2], tmp[3] };
        ((uint4*)wt)[(((size_t)f * 8 + w) * 16 + qf) * 64 + lane] = out;
    }
}

// Kernel 2: MFMA LSTM. Block = (f, group of 16 batches); 8 waves. Per step:
// gates^T C[16 batch rows x 512 gate cols] = h[16x128] (A, via tr-read) x W^T (B, regs).
// Wave w owns col-tiles {w, w+8, w+16, w+24} -> lane holds i,f,g,o of cell=16w+(l&15)
// for 4 batches -> c/h state fully in-register. h -> LDS (pos-permuted layout), re-read
// as A-frag with ds_read_b64_tr_b16; the k-permutation cancels between A and B.
__global__ __launch_bounds__(512, 1) void lstm_mfma(
    const float* __restrict__ x, const uint_t* __restrict__ wt,
    const float* __restrict__ wih_g, const float* __restrict__ bias_g,
    const int* __restrict__ gmeta, const int* __restrict__ guni,
    float* __restrict__ hout)
{
    __shared__ float xsh[T_][GB];                 // 16 KB, x^T per group
    __shared__ alignas(16) half_t hbuf[2][2048];  // 2 x 4 KB, pos-permuted h
    __shared__ int meta[GB][4];

    const int f = blockIdx.x >> 2, q = blockIdx.x & 3;
    const int tid = threadIdx.x;
    const int lane = tid & 63, w = tid >> 6;
    const int li = lane & 15, lg = lane >> 4;
    const int cell = 16 * w + li;
    const int r0 = lg * 4;
    // pos(k): bijection [0,128) -> [0,128) matching the tr-read recovery k=(lg)*8+e
    const int posc = ((cell & 4) ? 64 : 0) + ((cell >> 3) << 2) + (cell & 3);

    // ---- opaque weight preload: 16 x global_load_dwordx4 (B-frags, stay in VGPRs) ----
    uint4v wr[16];
    {
        const char* ws = (const char*)wt + ((((size_t)f * 8 + w) * 16) * 64 + lane) * 16;
#pragma unroll
        for (int qq = 0; qq < 16; ++qq) {
            unsigned long long a = (unsigned long long)(ws + (size_t)qq * 1024);
            asm volatile("global_load_dwordx4 %0, %1, off" : "=v"(wr[qq]) : "v"(a));
        }
        asm volatile("s_waitcnt vmcnt(0)");
        __builtin_amdgcn_sched_barrier(0);
    }

    if (tid < GB) ((int4*)meta)[tid] = ((const int4*)gmeta)[q * GB + tid];
    __syncthreads();

    // stage x^T [t][batch] f32 (4096 elems, 8 per thread)
#pragma unroll
    for (int j = 0; j < 8; ++j) {
        int idx = tid * 8 + j;
        int tt = idx >> 4, rr = idx & 15;
        xsh[tt][rr] = x[((size_t)meta[rr][0] * T_ + tt) * F_ + f];
    }
    ((unsigned long long*)&hbuf[0][0])[tid] = 0ULL;   // zero h buffer 0

    int bidv[4], bsv[4], bev[4];
#pragma unroll
    for (int r = 0; r < 4; ++r) {
        bidv[r] = meta[r0 + r][0];
        bsv[r]  = meta[r0 + r][1];
        bev[r]  = meta[r0 + r][2];
    }
    float wih[4], bb[4];
#pragma unroll
    for (int m = 0; m < 4; ++m) {
        wih[m] = wih_g[f * 512 + 128 * m + cell];
        bb[m]  = bias_g[f * 512 + 128 * m + cell];
    }
    const int sU = guni[2 * q], eU = guni[2 * q + 1];

    const unsigned hb0 = (unsigned)(size_t)&hbuf[0][0];   // LDS byte offset (low 32 bits)
    const unsigned trb = hb0 + (unsigned)(lane << 3);     // linear b64 slot per lane

    float cst[4] = {0.f, 0.f, 0.f, 0.f}, hst[4] = {0.f, 0.f, 0.f, 0.f};
    int pp = 0;
    __syncthreads();

    for (int t = sU; t < eU; ++t) {
        // A-frags: 8 hardware-transpose reads from hbuf[pp]; lane gets batch=li,
        // k = lg*8 + j per kt window (lo: e0..3 at kt*512, hi: e4..7 at 2048+kt*512)
        unsigned ta = trb + (unsigned)(pp << 12);
        uint2v l0, h0, l1, h1, l2, h2, l3, h3;
        asm volatile("ds_read_b64_tr_b16 %0, %1 offset:0"    : "=&v"(l0) : "v"(ta));
        asm volatile("ds_read_b64_tr_b16 %0, %1 offset:2048" : "=&v"(h0) : "v"(ta));
        asm volatile("ds_read_b64_tr_b16 %0, %1 offset:512"  : "=&v"(l1) : "v"(ta));
        asm volatile("ds_read_b64_tr_b16 %0, %1 offset:2560" : "=&v"(h1) : "v"(ta));
        asm volatile("ds_read_b64_tr_b16 %0, %1 offset:1024" : "=&v"(l2) : "v"(ta));
        asm volatile("ds_read_b64_tr_b16 %0, %1 offset:3072" : "=&v"(h2) : "v"(ta));
        asm volatile("ds_read_b64_tr_b16 %0, %1 offset:1536" : "=&v"(l3) : "v"(ta));
        asm volatile("ds_read_b64_tr_b16 %0, %1 offset:3584" : "=&v"(h3) : "v"(ta));
        float4v xv = *(const float4v*)&xsh[t][r0];
        asm volatile("s_waitcnt lgkmcnt(0)" ::: "memory");
        __builtin_amdgcn_sched_barrier(0);

        uint4v ua0 = { l0.x, l0.y, h0.x, h0.y };
        uint4v ua1 = { l1.x, l1.y, h1.x, h1.y };
        uint4v ua2 = { l2.x, l2.y, h2.x, h2.y };
        uint4v ua3 = { l3.x, l3.y, h3.x, h3.y };
        half8 a0 = __builtin_bit_cast(half8, ua0);
        half8 a1 = __builtin_bit_cast(half8, ua1);
        half8 a2 = __builtin_bit_cast(half8, ua2);
        half8 a3 = __builtin_bit_cast(half8, ua3);

        float4v d[4];
#pragma unroll
        for (int m = 0; m < 4; ++m) {
            float4v ci;
            ci.x = fmaf(xv.x, wih[m], bb[m]);
            ci.y = fmaf(xv.y, wih[m], bb[m]);
            ci.z = fmaf(xv.z, wih[m], bb[m]);
            ci.w = fmaf(xv.w, wih[m], bb[m]);
            ci = __builtin_amdgcn_mfma_f32_16x16x32_f16(a0, __builtin_bit_cast(half8, wr[m * 4 + 0]), ci, 0, 0, 0);
            ci = __builtin_amdgcn_mfma_f32_16x16x32_f16(a1, __builtin_bit_cast(half8, wr[m * 4 + 1]), ci, 0, 0, 0);
            ci = __builtin_amdgcn_mfma_f32_16x16x32_f16(a2, __builtin_bit_cast(half8, wr[m * 4 + 2]), ci, 0, 0, 0);
            ci = __builtin_amdgcn_mfma_f32_16x16x32_f16(a3, __builtin_bit_cast(half8, wr[m * 4 + 3]), ci, 0, 0, 0);
            d[m] = ci;
        }

        // nonlinearity + masked state update, fully in-register (4 batches/lane)
#pragma unroll
        for (int r = 0; r < 4; ++r) {
            float gi = sigm2(d[0][r]);
            float gf = sigm2(d[1][r]);
            float gg = tanh2(d[2][r]);
            float go = sigm2(d[3][r]);
            float cn = fmaf(gf, cst[r], gi * gg);
            bool mk = (t >= bsv[r]) & (t < bev[r]);
            cst[r] = mk ? cn : cst[r];
            float hn = go * tanh2(cst[r]);
            hst[r] = mk ? hn : hst[r];
        }

        // pack 4 f16 (batches r0..r0+3 of this cell) -> one b64 LDS write to hbuf[pp^1]
        half2_t pa, pb;
        pa[0] = (half_t)hst[0]; pa[1] = (half_t)hst[1];
        pb[0] = (half_t)hst[2]; pb[1] = (half_t)hst[3];
        uint2v uv = { __builtin_bit_cast(uint_t, pa), __builtin_bit_cast(uint_t, pb) };
        *reinterpret_cast<uint2v*>(&hbuf[pp ^ 1][posc * 16 + r0]) = uv;
        __syncthreads();
        pp ^= 1;
    }

#pragma unroll
    for (int r = 0; r < 4; ++r)
        hout[((size_t)bidv[r] * F_ + f) * H_ + cell] = hst[r];
}

// Kernel 3: per-batch epilogue: mean over H -> conv3 (pad 1) -> sigmoid gate -> gated fc.
__global__ void epilogue(const float* __restrict__ hout, const float* __restrict__ conv_w,
                         const float* __restrict__ fc_w, const float* __restrict__ fc_b,
                         float* __restrict__ out)
{
    const int b = blockIdx.x, t = threadIdx.x;   // 128 threads
    const int lane = t & 63, wv = t >> 6;
    __shared__ float part[2][16];
    __shared__ float gate_sh[16];

    float hv[16];
#pragma unroll
    for (int f = 0; f < 16; ++f) hv[f] = hout[((size_t)b * 16 + f) * 128 + t];

#pragma unroll
    for (int f = 0; f < 16; ++f) {
        float s = hv[f];
#pragma unroll
        for (int off = 32; off >= 1; off >>= 1) s += __shfl_down(s, off, 64);
        if (lane == 0) part[wv][f] = s;
    }
    __syncthreads();
    if (t < 16) gate_sh[t] = (part[0][t] + part[1][t]) * (1.0f / 128.0f);
    __syncthreads();
    float gate = 0.0f;
    if (t < 16) {
        float l  = (t > 0)  ? gate_sh[t - 1] : 0.0f;
        float mi = gate_sh[t];
        float r  = (t < 15) ? gate_sh[t + 1] : 0.0f;
        gate = sigm(fmaf(l, conv_w[0], fmaf(mi, conv_w[1], r * conv_w[2])));
    }
    __syncthreads();
    if (t < 16) gate_sh[t] = gate;
    __syncthreads();

    float acc0 = 0.0f, acc1 = 0.0f;
    const float2* fw2 = (const float2*)fc_w;
#pragma unroll
    for (int f = 0; f < 16; ++f) {
        float hg = hv[f] * gate_sh[f];
        float2 w2 = fw2[f * 128 + t];
        acc0 = fmaf(hg, w2.x, acc0);
        acc1 = fmaf(hg, w2.y, acc1);
    }
#pragma unroll
    for (int off = 32; off >= 1; off >>= 1) {
        acc0 += __shfl_down(acc0, off, 64);
        acc1 += __shfl_down(acc1, off, 64);
    }
    if (lane == 0) { part[wv][0] = acc0; part[wv][1] = acc1; }
    __syncthreads();
    if (t == 0) {
        out[b * 2 + 0] = part[0][0] + part[1][0] + fc_b[0];
        out[b * 2 + 1] = part[0][1] + part[1][1] + fc_b[1];
    }
}

extern "C" void kernel_launch(void* const* d_in, const int* in_sizes, int n_in,
                              void* d_out, int out_size, void* d_ws, size_t ws_size,
                              hipStream_t stream) {
    const float* x      = (const float*)d_in[0];
    const int*   index  = (const int*)  d_in[1];
    const float* W_ih   = (const float*)d_in[2];
    const float* W_hh   = (const float*)d_in[3];
    const float* bias   = (const float*)d_in[4];
    const float* conv_w = (const float*)d_in[5];
    const float* fc_w   = (const float*)d_in[6];
    const float* fc_b   = (const float*)d_in[7];
    float* out = (float*)d_out;

    uint_t* wt    = (uint_t*)d_ws;                                    // 2 MB
    float*  hout  = (float*)((char*)d_ws + 2 * 1024 * 1024);          // 512 KB
    int*    gmeta = (int*)((char*)d_ws + 2 * 1024 * 1024 + 512 * 1024);  // 1 KB
    int*    guni  = (int*)((char*)d_ws + 2 * 1024 * 1024 + 512 * 1024 + 1024); // 32 B

    make_sched<<<1, 64, 0, stream>>>(index, gmeta, guni);
    repack_w<<<dim3(F_, 8), 256, 0, stream>>>(W_hh, wt);
    lstm_mfma<<<64, 512, 0, stream>>>(x, wt, W_ih, bias, gmeta, guni, hout);
    epilogue<<<B_, 128, 0, stream>>>(hout, conv_w, fc_w, fc_b, out);
}

// Round 8
// 136.983 us; speedup vs baseline: 2.8120x; 1.7224x over previous
//
#include <hip/hip_runtime.h>

typedef _Float16 half_t;
typedef half_t half2_t __attribute__((ext_vector_type(2)));
typedef half_t half8  __attribute__((ext_vector_type(8)));
typedef unsigned int uint_t;
typedef uint_t uint4v __attribute__((ext_vector_type(4)));
typedef float float4v __attribute__((ext_vector_type(4)));

#define B_  64
#define T_  256
#define F_  16
#define H_  128
#define LOG2E 1.44269504f

__device__ __forceinline__ float rcp_(float x)  { return __builtin_amdgcn_rcpf(x); }
__device__ __forceinline__ float sigm2(float x) { return rcp_(1.0f + __builtin_amdgcn_exp2f(x * -LOG2E)); }
__device__ __forceinline__ float tanh2(float x) { return fmaf(rcp_(1.0f + __builtin_amdgcn_exp2f(x * (-2.0f * LOG2E))), 2.0f, -1.0f); }
__device__ __forceinline__ float sigm(float x)  { return rcp_(1.0f + __expf(-x)); }

// Kernel 0: rank batches by window length desc (approx-LPT dispatch order).
// tasks[r] = {b, s, e, 0}.
__global__ void make_sched(const int* __restrict__ index, int* __restrict__ tasks) {
    __shared__ int ln[B_];
    const int t = threadIdx.x;                 // 64
    const int s = index[2 * t], e = index[2 * t + 1];
    ln[t] = e - s;
    __syncthreads();
    int L = ln[t], r = 0;
    for (int j = 0; j < B_; ++j) r += (ln[j] > L) || (ln[j] == L && j < t);
    int4 v; v.x = t; v.y = s; v.z = e; v.w = 0;
    ((int4*)tasks)[r] = v;
}

// Kernel 1 (unchanged from R7, verified): W_hh [F,4H,H] fp32 -> f16 B-frags for
// mfma_f32_16x16x32_f16. Lane `lane` of wave w, frag q=m*4+kt, dword e2 holds the
// f16 pair for k = kt*32 + (lane>>4)*8 + 2*e2 (+1), col g = 128*m + 16*w + (lane&15).
__global__ void repack_w(const float* __restrict__ whh, uint_t* __restrict__ wt) {
    const int f = blockIdx.x, w = blockIdx.y, tid = threadIdx.x;  // 256 threads
    const int lane = tid & 63, q4 = tid >> 6;
    const int li = lane & 15, lg = lane >> 4;
    const float* base = whh + (size_t)f * 512 * 128;
#pragma unroll
    for (int qq = 0; qq < 4; ++qq) {
        const int qf = q4 * 4 + qq;
        const int m = qf >> 2, kt = qf & 3;
        const int g512 = 128 * m + 16 * w + li;
        uint_t tmp[4];
#pragma unroll
        for (int e2 = 0; e2 < 4; ++e2) {
            int k = kt * 32 + lg * 8 + 2 * e2;
            half2_t h;
            h[0] = (half_t)base[g512 * 128 + k];
            h[1] = (half_t)base[g512 * 128 + k + 1];
            tmp[e2] = __builtin_bit_cast(uint_t, h);
        }
        uint4 out = { tmp[0], tmp[1], tmp[2], tmp[3] };
        ((uint4*)wt)[(((size_t)f * 8 + w) * 16 + qf) * 64 + lane] = out;
    }
}

// Kernel 2: one block per (f, chain). 8 waves; wave w owns col-tiles {w,w+8,w+16,w+24}
// = the 4 gate types of cells 16w+li. A has 1 valid row (this batch) -> A-frag is a
// broadcast ds_read_b128 of h[kt*32+lg*8..+7]; all 16 A rows duplicate h, only C row 0
// (= .x, identical in every lane) is consumed. No masks: loop runs [s,e) exactly.
__global__ __launch_bounds__(512, 4) void lstm_mfma(
    const float* __restrict__ x, const uint_t* __restrict__ wt,
    const float* __restrict__ wih_g, const float* __restrict__ bias_g,
    const int* __restrict__ tasks, float* __restrict__ hout)
{
    __shared__ float xsh[T_];
    __shared__ alignas(16) half_t hbuf[2][H_];

    const int f = blockIdx.x & 15;
    const int4 tk = ((const int4*)tasks)[blockIdx.x >> 4];
    const int b = tk.x, s = tk.y, e = tk.z;
    const int tid = threadIdx.x, lane = tid & 63, w = tid >> 6;
    const int li = lane & 15, lg = lane >> 4;
    const int cell = 16 * w + li;

    // ---- opaque weight preload: 16 x global_load_dwordx4 (stay resident; R4-R7 proven) ----
    uint4v wr[16];
    {
        const char* ws = (const char*)wt + ((((size_t)f * 8 + w) * 16) * 64 + lane) * 16;
#pragma unroll
        for (int q = 0; q < 16; ++q) {
            unsigned long long a = (unsigned long long)(ws + (size_t)q * 1024);
            asm volatile("global_load_dwordx4 %0, %1, off" : "=v"(wr[q]) : "v"(a));
        }
        asm volatile("s_waitcnt vmcnt(0)");
        __builtin_amdgcn_sched_barrier(0);
    }

    float wih[4], bb[4];
#pragma unroll
    for (int m = 0; m < 4; ++m) {
        wih[m] = wih_g[f * 512 + 128 * m + cell];
        bb[m]  = bias_g[f * 512 + 128 * m + cell];
    }

    // stage this chain's x row (full T, simple & coalesced-ish; x is L2-resident)
    for (int idx = tid; idx < T_; idx += 512) xsh[idx] = x[((size_t)b * T_ + idx) * F_ + f];
    if (tid < H_) hbuf[0][tid] = (half_t)0.0f;

    float cst = 0.0f, hst = 0.0f;
    int pp = 0;
    __syncthreads();

    for (int t = s; t < e; ++t) {
        // A-frags: broadcast reads of current h (16B per kt window)
        const half_t* hb = &hbuf[pp][lg * 8];
        half8 a0 = *(const half8*)(hb + 0);
        half8 a1 = *(const half8*)(hb + 32);
        half8 a2 = *(const half8*)(hb + 64);
        half8 a3 = *(const half8*)(hb + 96);
        float xt = xsh[t];

        float4v d[4];
#pragma unroll
        for (int m = 0; m < 4; ++m) {
            float iv = fmaf(xt, wih[m], bb[m]);
            float4v ci = { iv, iv, iv, iv };
            ci = __builtin_amdgcn_mfma_f32_16x16x32_f16(a0, __builtin_bit_cast(half8, wr[m * 4 + 0]), ci, 0, 0, 0);
            ci = __builtin_amdgcn_mfma_f32_16x16x32_f16(a1, __builtin_bit_cast(half8, wr[m * 4 + 1]), ci, 0, 0, 0);
            ci = __builtin_amdgcn_mfma_f32_16x16x32_f16(a2, __builtin_bit_cast(half8, wr[m * 4 + 2]), ci, 0, 0, 0);
            ci = __builtin_amdgcn_mfma_f32_16x16x32_f16(a3, __builtin_bit_cast(half8, wr[m * 4 + 3]), ci, 0, 0, 0);
            d[m] = ci;
        }

        // row 0 of C is replicated into .x of every lane -> uniform scalar update
        float gi = sigm2(d[0].x);
        float gf = sigm2(d[1].x);
        float gg = tanh2(d[2].x);
        float go = sigm2(d[3].x);
        cst = fmaf(gf, cst, gi * gg);
        hst = go * tanh2(cst);

        if (lg == 0) hbuf[pp ^ 1][cell] = (half_t)hst;
        __syncthreads();
        pp ^= 1;
    }

    if (lg == 0) hout[((size_t)b * F_ + f) * H_ + cell] = hst;
}

// Kernel 3: per-batch epilogue: mean over H -> conv3 (pad 1) -> sigmoid gate -> gated fc.
__global__ void epilogue(const float* __restrict__ hout, const float* __restrict__ conv_w,
                         const float* __restrict__ fc_w, const float* __restrict__ fc_b,
                         float* __restrict__ out)
{
    const int b = blockIdx.x, t = threadIdx.x;   // 128 threads
    const int lane = t & 63, wv = t >> 6;
    __shared__ float part[2][16];
    __shared__ float gate_sh[16];

    float hv[16];
#pragma unroll
    for (int f = 0; f < 16; ++f) hv[f] = hout[((size_t)b * 16 + f) * 128 + t];

#pragma unroll
    for (int f = 0; f < 16; ++f) {
        float s = hv[f];
#pragma unroll
        for (int off = 32; off >= 1; off >>= 1) s += __shfl_down(s, off, 64);
        if (lane == 0) part[wv][f] = s;
    }
    __syncthreads();
    if (t < 16) gate_sh[t] = (part[0][t] + part[1][t]) * (1.0f / 128.0f);
    __syncthreads();
    float gate = 0.0f;
    if (t < 16) {
        float l  = (t > 0)  ? gate_sh[t - 1] : 0.0f;
        float mi = gate_sh[t];
        float r  = (t < 15) ? gate_sh[t + 1] : 0.0f;
        gate = sigm(fmaf(l, conv_w[0], fmaf(mi, conv_w[1], r * conv_w[2])));
    }
    __syncthreads();
    if (t < 16) gate_sh[t] = gate;
    __syncthreads();

    float acc0 = 0.0f, acc1 = 0.0f;
    const float2* fw2 = (const float2*)fc_w;
#pragma unroll
    for (int f = 0; f < 16; ++f) {
        float hg = hv[f] * gate_sh[f];
        float2 w2 = fw2[f * 128 + t];
        acc0 = fmaf(hg, w2.x, acc0);
        acc1 = fmaf(hg, w2.y, acc1);
    }
#pragma unroll
    for (int off = 32; off >= 1; off >>= 1) {
        acc0 += __shfl_down(acc0, off, 64);
        acc1 += __shfl_down(acc1, off, 64);
    }
    if (lane == 0) { part[wv][0] = acc0; part[wv][1] = acc1; }
    __syncthreads();
    if (t == 0) {
        out[b * 2 + 0] = part[0][0] + part[1][0] + fc_b[0];
        out[b * 2 + 1] = part[0][1] + part[1][1] + fc_b[1];
    }
}

extern "C" void kernel_launch(void* const* d_in, const int* in_sizes, int n_in,
                              void* d_out, int out_size, void* d_ws, size_t ws_size,
                              hipStream_t stream) {
    const float* x      = (const float*)d_in[0];
    const int*   index  = (const int*)  d_in[1];
    const float* W_ih   = (const float*)d_in[2];
    const float* W_hh   = (const float*)d_in[3];
    const float* bias   = (const float*)d_in[4];
    const float* conv_w = (const float*)d_in[5];
    const float* fc_w   = (const float*)d_in[6];
    const float* fc_b   = (const float*)d_in[7];
    float* out = (float*)d_out;

    uint_t* wt    = (uint_t*)d_ws;                                     // 2 MB
    float*  hout  = (float*)((char*)d_ws + 2 * 1024 * 1024);           // 512 KB
    int*    tasks = (int*)((char*)d_ws + 2 * 1024 * 1024 + 512 * 1024); // 1 KB

    make_sched<<<1, 64, 0, stream>>>(index, tasks);
    repack_w<<<dim3(F_, 8), 256, 0, stream>>>(W_hh, wt);
    lstm_mfma<<<1024, 512, 0, stream>>>(x, wt, W_ih, bias, tasks, hout);
    epilogue<<<B_, 128, 0, stream>>>(hout, conv_w, fc_w, fc_b, out);
}